// Round 14
// baseline (209.268 us; speedup 1.0000x reference)
//
#include <hip/hip_runtime.h>

#define TSTEPS 32
#define HID 1024
#define NCLS 10
#define BATCH 8
#define GGRP 32            // groups = H / TSTEPS
#define MROWS 8192         // BATCH * 1024 rows of the big GEMM
#define GK 2048            // K dim (W)
#define GN 1024            // N dim (HIDDEN)

typedef __attribute__((ext_vector_type(8))) short bf16x8;
typedef __attribute__((ext_vector_type(16))) float f32x16;

__device__ __forceinline__ unsigned short bf16_rne(float v) {
    unsigned u = __builtin_bit_cast(unsigned, v);
    return (unsigned short)((u + 0x7FFFu + ((u >> 16) & 1u)) >> 16);
}
__device__ __forceinline__ float bf16_f(unsigned short h) {
    unsigned u = (unsigned)h << 16;
    return __builtin_bit_cast(float, u);
}
__device__ __forceinline__ void gload16(const unsigned short* g, unsigned short* l) {
    __builtin_amdgcn_global_load_lds(
        (const __attribute__((address_space(1))) void*)g,
        (__attribute__((address_space(3))) void*)l, 16, 0, 0);
}

// Packed tile format: tile rows x 32 k, chunks of 8 bf16 (16B). chunk c:
// u=c>>6 (unit = rowband(u>>1, 32 rows) x khalf(u&1, 16 k)); w=c&63:
// row=(w&31), koct=(w>>5). Fragment = 64 consecutive chunks; lane l reads
// chunk (l&31)+32*(l>>5): contiguous 1KB, conflict-free ds_read_b128, linear
// global_load_lds staging (m104). A tiles are now built IN-KERNEL from x
// (conv fused): thread tid owns chunk tid (512 chunks = 512 threads), loads
// 8 contiguous float4 of x, conv+hi/lo-split, ds_write_b128.

// ---------------- w1 -> packed bf16 hi/lo B tiles (256-col tiles) ----------------
__global__ __launch_bounds__(256) void wpack_kernel(
    const float* __restrict__ wsrc, unsigned short* __restrict__ Bhi,
    unsigned short* __restrict__ Blo)
{
    const int kb  = blockIdx.x & 63;    // blockIdx.x = cbk*64 + kb
    const int cbk = blockIdx.x >> 6;    // 0..3 col-block
    const int tid = threadIdx.x;
#pragma unroll
    for (int cc = 0; cc < 4; ++cc) {
        int c = tid + cc * 256;         // chunk 0..1023
        int u = c >> 6, w = c & 63;
        int col = cbk * 256 + (u >> 1) * 32 + (w & 31);
        int k0  = kb * 32 + (u & 1) * 16 + (w >> 5) * 8;
        const float* pw = wsrc + ((size_t)col * 2048 + k0);
        bf16x8 h8, l8;
#pragma unroll
        for (int e = 0; e < 8; ++e) {
            float v = pw[e];
            unsigned short h = bf16_rne(v);
            h8[e] = (short)h;
            l8[e] = (short)bf16_rne(v - bf16_f(h));
        }
        size_t off = ((size_t)blockIdx.x * 1024 + c) * 8;
        *(bf16x8*)(Bhi + off) = h8;
        *(bf16x8*)(Blo + off) = l8;
    }
}

// ---------------- fused conv + MFMA GEMM (3-term bf16 split) + leaky scan ----------------
// 128x256 tile, BK=32, 8 waves (2x4 of 64x64), 512 threads.
// A: built in-kernel from x (conv fused), double-buffered LDS (2 x 16KB).
// B: global_load_lds, 3 buffers (3 x 32KB). LDS total 128KB -> 1 block/CU.
// iter KB: {lgkm0; barrier [tile KB ready]; READF(KB); CONVW(KB+1) [x-reg
// wait transitively drains B(KB+1) DMA: B issued BEFORE x each iter];
// STAGE_B(KB+2); LOADX(KB+2); lgkm0; MFMA(KB)}.
// Swizzle wgid=bx*64+by -> xcd=by%8: x panel (4MB) fetched once per XCD,
// shared by its 4 bx-blocks via L2; B (16MB) L2/L3-cached.
__global__ __launch_bounds__(512) void gemm_fused_kernel(
    const float4* __restrict__ x,
    const unsigned short* __restrict__ Bhi, const unsigned short* __restrict__ Blo,
    const float* __restrict__ cw, const float* __restrict__ cb,
    const float* __restrict__ bias,
    const float* __restrict__ beta1, const float* __restrict__ thr1,
    float* __restrict__ S)
{
    // shorts: A buf0 [0,8192) (hi 4096|lo 4096), A buf1 [8192,16384),
    // B bufs at 16384 + b*16384 (hi 8192|lo 8192). 128 KB total.
    // Scan epilogue reuses first 64 KB as [64][256] f32.
    __shared__ __align__(16) unsigned short sm[65536];

    const int tid = threadIdx.x;
    const int lane = tid & 63, wv = tid >> 6;
    const int wr = wv >> 2, wc = wv & 3;          // wave quadrant (2x4 of 64x64)
    const int by = blockIdx.x & 63;               // A row-panel (XCD = by%8)
    const int bx = blockIdx.x >> 6;               // B col-panel 0..3

    const float c0 = cw[0], c1 = cw[1], c2 = cw[2], c3 = cw[3], cbv = cb[0];

    // this thread's A chunk (chunk id = tid)
    const int cu_ = tid >> 6, cww = tid & 63;
    const int arow = (cu_ >> 1) * 32 + (cww & 31);
    const int ak0  = (cu_ & 1) * 16 + (cww >> 5) * 8;
    const float4* px = x + (size_t)(by * 128 + arow) * 2048 + ak0;

    const unsigned short* gBh = Bhi + (size_t)bx * 524288;
    const unsigned short* gBl = Blo + (size_t)bx * 524288;

    f32x16 acc[2][2];
#pragma unroll
    for (int i = 0; i < 2; ++i)
#pragma unroll
        for (int j = 0; j < 2; ++j) acc[i][j] = (f32x16)0.f;

    bf16x8 fr[16];              // [0..7]=A (i,kh,hi/lo), [8..15]=B (j,kh,hi/lo)
    float4 xs0[8], xs1[8];      // x staging, double-buffered (x(t) in set t&1)
    const int fo = ((lane & 31) + 32 * (lane >> 5)) * 8;

#define LOADX(XS, KB_)                                                           \
    {                                                                            \
        const float4* p_ = px + (size_t)(KB_) * 32;                              \
        _Pragma("unroll")                                                        \
        for (int e = 0; e < 8; ++e) XS[e] = p_[e];                               \
    }

#define CONVW(XS, KB_)                                                           \
    {                                                                            \
        bf16x8 h8, l8;                                                           \
        _Pragma("unroll")                                                        \
        for (int e = 0; e < 8; ++e) {                                            \
            float4 a = XS[e];                                                    \
            float v = a.x * c0 + a.y * c1 + a.z * c2 + a.w * c3 + cbv;           \
            unsigned short h = bf16_rne(v);                                      \
            h8[e] = (short)h;                                                    \
            l8[e] = (short)bf16_rne(v - bf16_f(h));                              \
        }                                                                        \
        unsigned short* d_ = sm + ((KB_) & 1) * 8192 + tid * 8;                  \
        *(bf16x8*)d_ = h8;                                                       \
        *(bf16x8*)(d_ + 4096) = l8;                                              \
    }

#define STAGE_B(KB_)                                                             \
    {                                                                            \
        unsigned short* dst = sm + 16384 + ((KB_) % 3) * 16384;                  \
        const size_t bo = (size_t)(KB_) * 8192 + tid * 8;                        \
        gload16(gBh + bo, dst + tid * 8);                                        \
        gload16(gBh + bo + 4096, dst + 4096 + tid * 8);                          \
        gload16(gBl + bo, dst + 8192 + tid * 8);                                 \
        gload16(gBl + bo + 4096, dst + 12288 + tid * 8);                         \
    }

#define READF(KB_)                                                               \
    {                                                                            \
        const unsigned short* ab = sm + ((KB_) & 1) * 8192;                      \
        const unsigned short* bb = sm + 16384 + ((KB_) % 3) * 16384;             \
        _Pragma("unroll")                                                        \
        for (int i = 0; i < 2; ++i)                                              \
            _Pragma("unroll")                                                    \
            for (int kh = 0; kh < 2; ++kh) {                                     \
                int ua = (((wr * 2 + i) * 2 + kh) << 9) + fo;                    \
                fr[(i * 2 + kh) * 2 + 0] = *(const bf16x8*)(ab + ua);            \
                fr[(i * 2 + kh) * 2 + 1] = *(const bf16x8*)(ab + 4096 + ua);     \
            }                                                                    \
        _Pragma("unroll")                                                        \
        for (int j = 0; j < 2; ++j)                                              \
            _Pragma("unroll")                                                    \
            for (int kh = 0; kh < 2; ++kh) {                                     \
                int ub = (((wc * 2 + j) * 2 + kh) << 9) + fo;                    \
                fr[8 + (j * 2 + kh) * 2 + 0] = *(const bf16x8*)(bb + ub);        \
                fr[8 + (j * 2 + kh) * 2 + 1] = *(const bf16x8*)(bb + 8192 + ub); \
            }                                                                    \
    }

#define MFMAF()                                                                  \
    {                                                                            \
        _Pragma("unroll")                                                        \
        for (int kh = 0; kh < 2; ++kh) {                                         \
            _Pragma("unroll")                                                    \
            for (int i = 0; i < 2; ++i)                                          \
                _Pragma("unroll")                                                \
                for (int j = 0; j < 2; ++j)                                      \
                    acc[i][j] = __builtin_amdgcn_mfma_f32_32x32x16_bf16(         \
                        fr[(i * 2 + kh) * 2], fr[8 + (j * 2 + kh) * 2],          \
                        acc[i][j], 0, 0, 0);                                     \
            _Pragma("unroll")                                                    \
            for (int i = 0; i < 2; ++i)                                          \
                _Pragma("unroll")                                                \
                for (int j = 0; j < 2; ++j)                                      \
                    acc[i][j] = __builtin_amdgcn_mfma_f32_32x32x16_bf16(         \
                        fr[(i * 2 + kh) * 2], fr[8 + (j * 2 + kh) * 2 + 1],      \
                        acc[i][j], 0, 0, 0);                                     \
            _Pragma("unroll")                                                    \
            for (int i = 0; i < 2; ++i)                                          \
                _Pragma("unroll")                                                \
                for (int j = 0; j < 2; ++j)                                      \
                    acc[i][j] = __builtin_amdgcn_mfma_f32_32x32x16_bf16(         \
                        fr[(i * 2 + kh) * 2 + 1], fr[8 + (j * 2 + kh) * 2],      \
                        acc[i][j], 0, 0, 0);                                     \
        }                                                                        \
    }

// ITER(XC, XL, KB, DOSTAGE, DOLOAD, DOCONV): see header comment.
#define ITER(XC, XL, KB, DOSTAGE, DOLOAD, DOCONV)                                \
    {                                                                            \
        asm volatile("s_waitcnt lgkmcnt(0)" ::: "memory");                       \
        __builtin_amdgcn_sched_barrier(0);                                       \
        __builtin_amdgcn_s_barrier();                                            \
        READF(KB);                                                               \
        if (DOCONV) CONVW(XC, (KB) + 1);                                         \
        if (DOSTAGE) STAGE_B((KB) + 2);                                          \
        __builtin_amdgcn_sched_barrier(0);  /* pin: B-DMA issues before x */     \
        if (DOLOAD) LOADX(XL, (KB) + 2);                                         \
        asm volatile("s_waitcnt lgkmcnt(0)" ::: "memory");                       \
        __builtin_amdgcn_sched_barrier(0);                                       \
        __builtin_amdgcn_s_setprio(1);                                           \
        MFMAF();                                                                 \
        __builtin_amdgcn_s_setprio(0);                                           \
    }

    // prologue: B(0),x(0),B(1),x(1) issued (B before x); conv A(0); barrier.
    STAGE_B(0);
    __builtin_amdgcn_sched_barrier(0);
    LOADX(xs0, 0);
    __builtin_amdgcn_sched_barrier(0);
    STAGE_B(1);
    __builtin_amdgcn_sched_barrier(0);
    LOADX(xs1, 1);
    CONVW(xs0, 0);      // x(0)-wait drains B(0) (older) -> tile 0 B in LDS
    asm volatile("s_waitcnt lgkmcnt(0)" ::: "memory");
    __builtin_amdgcn_sched_barrier(0);
    __builtin_amdgcn_s_barrier();       // tile 0 (A writes + B DMA) visible

    ITER(xs1, xs0, 0, 1, 1, 1);         // READF(0), conv A(1), B(2), x(2), MFMA(0)
    for (int kb = 1; kb < 61; kb += 2) {
        ITER(xs0, xs1, kb, 1, 1, 1);       // odd KB
        ITER(xs1, xs0, kb + 1, 1, 1, 1);   // even KB
    }
    ITER(xs0, xs1, 61, 1, 1, 1);        // conv A(62), B(63), x(63)
    ITER(xs1, xs0, 62, 0, 0, 1);        // conv A(63); x(63)-wait drains B(63)
    // iter 63
    asm volatile("s_waitcnt lgkmcnt(0)" ::: "memory");
    __builtin_amdgcn_sched_barrier(0);
    __builtin_amdgcn_s_barrier();
    READF(63);
    asm volatile("s_waitcnt lgkmcnt(0)" ::: "memory");
    __builtin_amdgcn_sched_barrier(0);
    MFMAF();
    __syncthreads();    // all waves done with LDS before scan epilogue reuses it

    // ---- fused leaky scan over t (reuse LDS as [64][256] f32 buffer, 64 KB) ----
    float* sb = (float*)sm;
    const float bclamp = fminf(fmaxf(beta1[0], 0.f), 1.f);
    const float th = thr1[0];
    const int sbg = tid >> 8;          // 0..1 ((b,g) group within band)
    const int scol = tid & 255;        // 0..255
    const float bv = bias[bx * 256 + scol];

#pragma unroll
    for (int band = 0; band < 2; ++band) {
        if (wr == band) {
#pragma unroll
            for (int i = 0; i < 2; ++i)
#pragma unroll
                for (int j = 0; j < 2; ++j)
#pragma unroll
                    for (int r = 0; r < 16; ++r) {
                        int lr = i * 32 + (r & 3) + 8 * (r >> 2) + 4 * (lane >> 5);
                        int lc = wc * 64 + j * 32 + (lane & 31);
                        sb[lr * 256 + lc] = acc[i][j][r];
                    }
        }
        __syncthreads();
        float mem = 0.f, cnt = 0.f;
#pragma unroll
        for (int t = 0; t < TSTEPS; ++t) {
            float u = sb[(sbg * 32 + t) * 256 + scol] + bv;
            mem = bclamp * mem + u;
            float spk = mem > th ? 1.f : 0.f;
            mem -= spk * th;
            cnt += spk;
        }
        int bgg = by * 4 + band * 2 + sbg;
        S[(size_t)bgg * GN + bx * 256 + scol] = cnt;
        __syncthreads();
    }
}

// ---------------- FC2 ----------------
__global__ __launch_bounds__(256) void fc2_kernel(
    const float* __restrict__ s, const float* __restrict__ w2,
    const float* __restrict__ b2, float* __restrict__ h2)
{
    int bg  = blockIdx.x;     // 0..255
    int tid = threadIdx.x;
    const float* sp = s + (size_t)bg * HID;
    float part[NCLS];
#pragma unroll
    for (int c = 0; c < NCLS; ++c) part[c] = 0.f;
    for (int d = tid; d < HID; d += 256) {
        float sv = sp[d];
#pragma unroll
        for (int c = 0; c < NCLS; ++c) part[c] += sv * w2[c * HID + d];
    }
#pragma unroll
    for (int c = 0; c < NCLS; ++c)
        for (int off = 32; off > 0; off >>= 1)
            part[c] += __shfl_down(part[c], off, 64);
    __shared__ float red[NCLS][4];
    int wave = tid >> 6, lanei = tid & 63;
    if (lanei == 0)
#pragma unroll
        for (int c = 0; c < NCLS; ++c) red[c][wave] = part[c];
    __syncthreads();
    if (tid < NCLS) {
        float v = red[tid][0] + red[tid][1] + red[tid][2] + red[tid][3] + b2[tid];
        h2[bg * NCLS + tid] = v;
    }
}

// ---------------- scan over G + softmax ----------------
__global__ __launch_bounds__(128) void scan2_kernel(
    const float* __restrict__ h2, const float* __restrict__ beta2,
    const float* __restrict__ thr2, float* __restrict__ out)
{
    __shared__ float logits[BATCH][NCLS];
    int t = threadIdx.x;
    if (t < BATCH * NCLS) {
        int b = t / NCLS, c = t % NCLS;
        float bb = fminf(fmaxf(beta2[0], 0.f), 1.f);
        float th = thr2[0];
        float mem = 0.f, lg = 0.f;
        for (int g = 0; g < GGRP; ++g) {
            float u = h2[(b * GGRP + g) * NCLS + c];
            mem = bb * mem + u;
            float spk = mem > th ? 1.f : 0.f;
            mem -= spk * th;
            lg += spk;
        }
        logits[b][c] = lg;
    }
    __syncthreads();
    if (t < BATCH) {
        float mx = -1e30f;
        for (int c = 0; c < NCLS; ++c) mx = fmaxf(mx, logits[t][c]);
        float e[NCLS];
        float sum = 0.f;
        for (int c = 0; c < NCLS; ++c) { e[c] = expf(logits[t][c] - mx); sum += e[c]; }
        for (int c = 0; c < NCLS; ++c) out[t * NCLS + c] = e[c] / sum;
    }
}

extern "C" void kernel_launch(void* const* d_in, const int* in_sizes, int n_in,
                              void* d_out, int out_size, void* d_ws, size_t ws_size,
                              hipStream_t stream)
{
    const float* x     = (const float*)d_in[0];
    const float* cw    = (const float*)d_in[1];
    const float* cb    = (const float*)d_in[2];
    const float* w1    = (const float*)d_in[3];
    const float* b1    = (const float*)d_in[4];
    const float* beta1 = (const float*)d_in[5];
    const float* thr1  = (const float*)d_in[6];
    const float* w2    = (const float*)d_in[7];
    const float* b2    = (const float*)d_in[8];
    const float* beta2 = (const float*)d_in[9];
    const float* thr2  = (const float*)d_in[10];
    float* out = (float*)d_out;

    // ws: Bhi 4MB | Blo 4MB | s 1MB | h2 10KB (~9MB)
    unsigned short* bhi = (unsigned short*)d_ws;
    unsigned short* blo = bhi + (size_t)GN * GK;
    float* s  = (float*)(blo + (size_t)GN * GK);
    float* h2 = s + (size_t)BATCH * GGRP * HID;

    wpack_kernel     <<<256, 256, 0, stream>>>(w1, bhi, blo);
    gemm_fused_kernel<<<256, 512, 0, stream>>>((const float4*)x, bhi, blo, cw, cb,
                                               b1, beta1, thr1, s);
    fc2_kernel       <<<256, 256, 0, stream>>>(s, w2, b2, h2);
    scan2_kernel     <<<1, 128, 0, stream>>>(h2, beta2, thr2, out);
}

// Round 15
// 155.217 us; speedup vs baseline: 1.3482x; 1.3482x over previous
//
#include <hip/hip_runtime.h>

#define TSTEPS 32
#define HID 1024
#define NCLS 10
#define BATCH 8
#define GGRP 32            // groups = H / TSTEPS
#define MROWS 8192         // BATCH * 1024 rows of the big GEMM
#define GK 2048            // K dim (W)
#define GN 1024            // N dim (HIDDEN)
#define BUFSH 24576        // shorts per LDS buffer (A 8K + B 16K shorts)
#define CLDS 40            // conv LDS row pitch in shorts (80B, 16B aligned)

typedef __attribute__((ext_vector_type(8))) short bf16x8;
typedef __attribute__((ext_vector_type(16))) float f32x16;

__device__ __forceinline__ unsigned short bf16_rne(float v) {
    unsigned u = __builtin_bit_cast(unsigned, v);
    return (unsigned short)((u + 0x7FFFu + ((u >> 16) & 1u)) >> 16);
}
__device__ __forceinline__ float bf16_f(unsigned short h) {
    unsigned u = (unsigned)h << 16;
    return __builtin_bit_cast(float, u);
}
__device__ __forceinline__ void gload16(const unsigned short* g, unsigned short* l) {
    __builtin_amdgcn_global_load_lds(
        (const __attribute__((address_space(1))) void*)g,
        (__attribute__((address_space(3))) void*)l, 16, 0, 0);
}

// A tile = 128 rows x 32 k, 512 chunks of 8 bf16 (16B): chunk c: u=c>>6 (unit =
// rowband(u>>1, 32 rows) x khalf(u&1, 16 k)), w=c&63: row=(w&31), koct=(w>>5).
// B tile = 256 rows x 32 k, 1024 chunks, same unit scheme (16 units).
// MFMA fragment read = 64 consecutive chunks (lane l -> chunk (l&31)+32*(l>>5))
// -> contiguous 1KB, conflict-free; global_load_lds staging stays linear.

// ---------------- merged producer: conv->A tiles (blocks 0..4095) and
// ---------------- w1->B tiles (blocks 4096..4351) ----------------
__global__ __launch_bounds__(256) void pack_kernel(
    const float4* __restrict__ x, const float* __restrict__ cw,
    const float* __restrict__ cb,
    unsigned short* __restrict__ Ahi, unsigned short* __restrict__ Alo,
    const float* __restrict__ wsrc, unsigned short* __restrict__ Bhi,
    unsigned short* __restrict__ Blo)
{
    const int tid = threadIdx.x;
    if (blockIdx.x < 4096) {
        // ---- conv + hi/lo split + pack (LDS-staged, coalesced reads) ----
        __shared__ __align__(16) unsigned short lh[128 * CLDS];
        __shared__ __align__(16) unsigned short ll[128 * CLDS];
        const int rb = blockIdx.x >> 6;     // 0..63 row-block
        const int kb = blockIdx.x & 63;     // 0..63 k-block
        const float c0 = cw[0], c1 = cw[1], c2 = cw[2], c3 = cw[3], cbv = cb[0];

#pragma unroll
        for (int p = 0; p < 16; ++p) {
            int i = p * 256 + tid;          // 0..4095 over [128 rows][32 px]
            int row = i >> 5, px = i & 31;
            float4 a = x[(size_t)(rb * 128 + row) * 2048 + kb * 32 + px];
            float v = a.x * c0 + a.y * c1 + a.z * c2 + a.w * c3 + cbv;
            unsigned short h = bf16_rne(v);
            lh[row * CLDS + px] = h;
            ll[row * CLDS + px] = bf16_rne(v - bf16_f(h));
        }
        __syncthreads();

#pragma unroll
        for (int cc = 0; cc < 2; ++cc) {
            int c = tid + cc * 256;         // chunk 0..511
            int u = c >> 6, w = c & 63;
            int row = (u >> 1) * 32 + (w & 31);
            int ko  = (u & 1) * 2 + (w >> 5);   // k-octet 0..3
            bf16x8 h8 = *(const bf16x8*)(lh + row * CLDS + ko * 8);
            bf16x8 l8 = *(const bf16x8*)(ll + row * CLDS + ko * 8);
            size_t off = ((size_t)blockIdx.x * 512 + c) * 8;
            *(bf16x8*)(Ahi + off) = h8;
            *(bf16x8*)(Alo + off) = l8;
        }
    } else {
        // ---- w1 -> packed bf16 hi/lo B tiles (256-col tiles) ----
        const int bid = blockIdx.x - 4096;  // 0..255
        const int kb  = bid & 63;           // bid = cbk*64 + kb
        const int cbk = bid >> 6;           // 0..3 col-block
#pragma unroll
        for (int cc = 0; cc < 4; ++cc) {
            int c = tid + cc * 256;         // chunk 0..1023
            int u = c >> 6, w = c & 63;
            int col = cbk * 256 + (u >> 1) * 32 + (w & 31);
            int k0  = kb * 32 + (u & 1) * 16 + (w >> 5) * 8;
            const float* pw = wsrc + ((size_t)col * 2048 + k0);
            bf16x8 h8, l8;
#pragma unroll
            for (int e = 0; e < 8; ++e) {
                float v = pw[e];
                unsigned short h = bf16_rne(v);
                h8[e] = (short)h;
                l8[e] = (short)bf16_rne(v - bf16_f(h));
            }
            size_t off = ((size_t)bid * 1024 + c) * 8;
            *(bf16x8*)(Bhi + off) = h8;
            *(bf16x8*)(Blo + off) = l8;
        }
    }
}

// ---------------- MFMA GEMM (3-term bf16 split, 32x32x16) + fused scan ----------------
// 128x256 tile, BK=32, 8 waves (2x4 of 64x64), 512 threads, triple-buffered LDS.
// One-step software pipeline (R8-measured best, 154.9us):
//   iteration KB: tile KB-1's frags in regs (set SC) -> MFMA them;
//   read tile KB's frags (set SN) from buf KB%3, reads fly under MFMAs;
//   STAGE tile KB+2 into buf (KB+2)%3 (freed: tile KB-1 fully read by all
//   waves, guaranteed by lgkmcnt(0)+barrier this iteration).
// Wait math: entry outstanding = my 6 loads each of tiles KB, KB+1 ->
//   vmcnt(6) = tile KB resident (vmcnt(0) at KB=63, where only 6 remain).
__global__ __launch_bounds__(512) void gemm_scan_kernel(
    const unsigned short* __restrict__ Ahi, const unsigned short* __restrict__ Alo,
    const unsigned short* __restrict__ Bhi, const unsigned short* __restrict__ Blo,
    const float* __restrict__ bias,
    const float* __restrict__ beta1, const float* __restrict__ thr1,
    float* __restrict__ S)
{
    // per buffer (shorts): Ahi[0,4096) Alo[4096,8192) Bhi[8192,16384) Blo[16384,24576)
    __shared__ __align__(16) unsigned short sm[3 * BUFSH];   // 147,456 B

    const int tid = threadIdx.x;
    const int lane = tid & 63, wv = tid >> 6;
    const int wr = wv >> 2, wc = wv & 3;          // wave quadrant (2x4 of 64x64)
    const int by = blockIdx.x & 63;               // A row-panel (XCD = by%8)
    const int bx = blockIdx.x >> 6;               // B col-panel 0..3

    const unsigned short* gAh = Ahi + (size_t)by * 262144;
    const unsigned short* gAl = Alo + (size_t)by * 262144;
    const unsigned short* gBh = Bhi + (size_t)bx * 524288;
    const unsigned short* gBl = Blo + (size_t)bx * 524288;

    f32x16 acc[2][2];
#pragma unroll
    for (int i = 0; i < 2; ++i)
#pragma unroll
        for (int j = 0; j < 2; ++j) acc[i][j] = (f32x16)0.f;

    // frag sets: [set][0..7]=A (i,kh,hi/lo), [set][8..15]=B (j,kh,hi/lo)
    bf16x8 fr[2][16];

#define STAGE(buf, kb_)                                                          \
    {                                                                            \
        unsigned short* dst = sm + (buf) * BUFSH;                                \
        const size_t ao = (size_t)(kb_) * 4096 + tid * 8;                        \
        const size_t bo = (size_t)(kb_) * 8192 + tid * 8;                        \
        gload16(gAh + ao, dst + tid * 8);                                        \
        gload16(gAl + ao, dst + 4096 + tid * 8);                                 \
        gload16(gBh + bo, dst + 8192 + tid * 8);                                 \
        gload16(gBh + bo + 4096, dst + 12288 + tid * 8);                         \
        gload16(gBl + bo, dst + 16384 + tid * 8);                                \
        gload16(gBl + bo + 4096, dst + 20480 + tid * 8);                         \
    }

#define READF(s, bufp)                                                           \
    {                                                                            \
        const unsigned short* bp_ = (bufp);                                      \
        _Pragma("unroll")                                                        \
        for (int i = 0; i < 2; ++i)                                              \
            _Pragma("unroll")                                                    \
            for (int kh = 0; kh < 2; ++kh) {                                     \
                int ua = (((wr * 2 + i) * 2 + kh) << 9) + fo;                    \
                fr[s][(i * 2 + kh) * 2 + 0] = *(const bf16x8*)(bp_ + ua);        \
                fr[s][(i * 2 + kh) * 2 + 1] = *(const bf16x8*)(bp_ + 4096 + ua); \
            }                                                                    \
        _Pragma("unroll")                                                        \
        for (int j = 0; j < 2; ++j)                                              \
            _Pragma("unroll")                                                    \
            for (int kh = 0; kh < 2; ++kh) {                                     \
                int ub = (((wc * 2 + j) * 2 + kh) << 9) + fo;                    \
                fr[s][8 + (j * 2 + kh) * 2 + 0] = *(const bf16x8*)(bp_ + 8192 + ub);  \
                fr[s][8 + (j * 2 + kh) * 2 + 1] = *(const bf16x8*)(bp_ + 16384 + ub); \
            }                                                                    \
    }

#define MFMAF(s)                                                                 \
    {                                                                            \
        _Pragma("unroll")                                                        \
        for (int kh = 0; kh < 2; ++kh) {                                         \
            _Pragma("unroll")                                                    \
            for (int i = 0; i < 2; ++i)                                          \
                _Pragma("unroll")                                                \
                for (int j = 0; j < 2; ++j)                                      \
                    acc[i][j] = __builtin_amdgcn_mfma_f32_32x32x16_bf16(         \
                        fr[s][(i * 2 + kh) * 2], fr[s][8 + (j * 2 + kh) * 2],    \
                        acc[i][j], 0, 0, 0);                                     \
            _Pragma("unroll")                                                    \
            for (int i = 0; i < 2; ++i)                                          \
                _Pragma("unroll")                                                \
                for (int j = 0; j < 2; ++j)                                      \
                    acc[i][j] = __builtin_amdgcn_mfma_f32_32x32x16_bf16(         \
                        fr[s][(i * 2 + kh) * 2], fr[s][8 + (j * 2 + kh) * 2 + 1],\
                        acc[i][j], 0, 0, 0);                                     \
            _Pragma("unroll")                                                    \
            for (int i = 0; i < 2; ++i)                                          \
                _Pragma("unroll")                                                \
                for (int j = 0; j < 2; ++j)                                      \
                    acc[i][j] = __builtin_amdgcn_mfma_f32_32x32x16_bf16(         \
                        fr[s][(i * 2 + kh) * 2 + 1], fr[s][8 + (j * 2 + kh) * 2],\
                        acc[i][j], 0, 0, 0);                                     \
        }                                                                        \
    }

#define KSTEP(SC, SN, KB, DOSTAGE)                                               \
    {                                                                            \
        if ((KB) < 63) asm volatile("s_waitcnt vmcnt(6)" ::: "memory");          \
        else           asm volatile("s_waitcnt vmcnt(0)" ::: "memory");          \
        asm volatile("s_waitcnt lgkmcnt(0)" ::: "memory");                       \
        __builtin_amdgcn_sched_barrier(0);                                       \
        __builtin_amdgcn_s_barrier();                                            \
        if (DOSTAGE) STAGE(((KB) + 2) % 3, (KB) + 2);                            \
        READF(SN, sm + ((KB) % 3) * BUFSH);                                      \
        MFMAF(SC);                                                               \
    }

    // prologue: stage tiles 0,1,2; wait tile0 (18 outstanding -> 12); frags(0)
    STAGE(0, 0);
    STAGE(1, 1);
    STAGE(2, 2);
    asm volatile("s_waitcnt vmcnt(12)" ::: "memory");
    __builtin_amdgcn_s_barrier();
    const int fo = ((lane & 31) + 32 * (lane >> 5)) * 8;
    READF(0, sm);

    for (int kb = 1; kb < 63; kb += 2) {
        KSTEP(0, 1, kb, (kb <= 61));       // MFMA tile kb-1 (set0), read tile kb
        KSTEP(1, 0, kb + 1, (kb + 1 <= 61)); // MFMA tile kb (set1), read tile kb+1
    }
    KSTEP(0, 1, 63, 0);                    // MFMA 62, read 63
    // epilogue: MFMA tile 63
    asm volatile("s_waitcnt lgkmcnt(0)" ::: "memory");
    __builtin_amdgcn_sched_barrier(0);
    MFMAF(1);
    __syncthreads();   // all waves done with LDS before scan epilogue reuses it

    // ---- fused leaky scan over t (reuse LDS as [64][256] f32 buffer, 64 KB) ----
    float* sb = (float*)sm;
    const float bclamp = fminf(fmaxf(beta1[0], 0.f), 1.f);
    const float th = thr1[0];
    const int sbg = tid >> 8;          // 0..1 ((b,g) group within band)
    const int scol = tid & 255;        // 0..255
    const float bv = bias[bx * 256 + scol];

#pragma unroll
    for (int band = 0; band < 2; ++band) {
        if (wr == band) {
#pragma unroll
            for (int i = 0; i < 2; ++i)
#pragma unroll
                for (int j = 0; j < 2; ++j)
#pragma unroll
                    for (int r = 0; r < 16; ++r) {
                        int lr = i * 32 + (r & 3) + 8 * (r >> 2) + 4 * (lane >> 5);
                        int lc = wc * 64 + j * 32 + (lane & 31);
                        sb[lr * 256 + lc] = acc[i][j][r];
                    }
        }
        __syncthreads();
        float mem = 0.f, cnt = 0.f;
#pragma unroll
        for (int t = 0; t < TSTEPS; ++t) {
            float u = sb[(sbg * 32 + t) * 256 + scol] + bv;
            mem = bclamp * mem + u;
            float spk = mem > th ? 1.f : 0.f;
            mem -= spk * th;
            cnt += spk;
        }
        int bgg = by * 4 + band * 2 + sbg;
        S[(size_t)bgg * GN + bx * 256 + scol] = cnt;
        __syncthreads();
    }
}

// ---------------- FC2 ----------------
__global__ __launch_bounds__(256) void fc2_kernel(
    const float* __restrict__ s, const float* __restrict__ w2,
    const float* __restrict__ b2, float* __restrict__ h2)
{
    int bg  = blockIdx.x;     // 0..255
    int tid = threadIdx.x;
    const float* sp = s + (size_t)bg * HID;
    float part[NCLS];
#pragma unroll
    for (int c = 0; c < NCLS; ++c) part[c] = 0.f;
    for (int d = tid; d < HID; d += 256) {
        float sv = sp[d];
#pragma unroll
        for (int c = 0; c < NCLS; ++c) part[c] += sv * w2[c * HID + d];
    }
#pragma unroll
    for (int c = 0; c < NCLS; ++c)
        for (int off = 32; off > 0; off >>= 1)
            part[c] += __shfl_down(part[c], off, 64);
    __shared__ float red[NCLS][4];
    int wave = tid >> 6, lanei = tid & 63;
    if (lanei == 0)
#pragma unroll
        for (int c = 0; c < NCLS; ++c) red[c][wave] = part[c];
    __syncthreads();
    if (tid < NCLS) {
        float v = red[tid][0] + red[tid][1] + red[tid][2] + red[tid][3] + b2[tid];
        h2[bg * NCLS + tid] = v;
    }
}

// ---------------- scan over G + softmax ----------------
__global__ __launch_bounds__(128) void scan2_kernel(
    const float* __restrict__ h2, const float* __restrict__ beta2,
    const float* __restrict__ thr2, float* __restrict__ out)
{
    __shared__ float logits[BATCH][NCLS];
    int t = threadIdx.x;
    if (t < BATCH * NCLS) {
        int b = t / NCLS, c = t % NCLS;
        float bb = fminf(fmaxf(beta2[0], 0.f), 1.f);
        float th = thr2[0];
        float mem = 0.f, lg = 0.f;
        for (int g = 0; g < GGRP; ++g) {
            float u = h2[(b * GGRP + g) * NCLS + c];
            mem = bb * mem + u;
            float spk = mem > th ? 1.f : 0.f;
            mem -= spk * th;
            lg += spk;
        }
        logits[b][c] = lg;
    }
    __syncthreads();
    if (t < BATCH) {
        float mx = -1e30f;
        for (int c = 0; c < NCLS; ++c) mx = fmaxf(mx, logits[t][c]);
        float e[NCLS];
        float sum = 0.f;
        for (int c = 0; c < NCLS; ++c) { e[c] = expf(logits[t][c] - mx); sum += e[c]; }
        for (int c = 0; c < NCLS; ++c) out[t * NCLS + c] = e[c] / sum;
    }
}

extern "C" void kernel_launch(void* const* d_in, const int* in_sizes, int n_in,
                              void* d_out, int out_size, void* d_ws, size_t ws_size,
                              hipStream_t stream)
{
    const float* x     = (const float*)d_in[0];
    const float* cw    = (const float*)d_in[1];
    const float* cb    = (const float*)d_in[2];
    const float* w1    = (const float*)d_in[3];
    const float* b1    = (const float*)d_in[4];
    const float* beta1 = (const float*)d_in[5];
    const float* thr1  = (const float*)d_in[6];
    const float* w2    = (const float*)d_in[7];
    const float* b2    = (const float*)d_in[8];
    const float* beta2 = (const float*)d_in[9];
    const float* thr2  = (const float*)d_in[10];
    float* out = (float*)d_out;

    // ws: Ahi 32MB | Alo 32MB | Bhi 4MB | Blo 4MB | s 1MB | h2 10KB (~73MB)
    unsigned short* ahi = (unsigned short*)d_ws;
    unsigned short* alo = ahi + (size_t)MROWS * GK;
    unsigned short* bhi = alo + (size_t)MROWS * GK;
    unsigned short* blo = bhi + (size_t)GN * GK;
    float* s  = (float*)(blo + (size_t)GN * GK);
    float* h2 = s + (size_t)BATCH * GGRP * HID;

    pack_kernel     <<<4352, 256, 0, stream>>>((const float4*)x, cw, cb, ahi, alo,
                                               w1, bhi, blo);
    gemm_scan_kernel<<<256, 512, 0, stream>>>(ahi, alo, bhi, blo, b1, beta1, thr1, s);
    fc2_kernel      <<<256, 256, 0, stream>>>(s, w2, b2, h2);
    scan2_kernel    <<<1, 128, 0, stream>>>(h2, beta2, thr2, out);
}